// Round 7
// baseline (469.527 us; speedup 1.0000x reference)
//
#include <hip/hip_runtime.h>
#include <hip/hip_bf16.h>

// FP8Linear: out[M=8192][N=4096] = X @ (qweight*scale)^T.
// fp32->bf16 cvt, then 256x256/BK=64 bf16 MFMA GEMM, 8-phase schedule with
// ONE barrier per phase (per-wave compiler-managed lgkm drains make the
// pre-MFMA barrier redundant), counted vmcnt(6), XOR-swizzled LDS (0-conflict,
// measured), LDS-shuffled coalesced nontemporal fp32 epilogue.

typedef __attribute__((ext_vector_type(4))) float  f32x4;
typedef __attribute__((ext_vector_type(8))) short  bf16x8;
typedef __attribute__((ext_vector_type(8))) unsigned short u16x8;

static constexpr int Mdim = 8192, Ndim = 4096, Kdim = 4096;
static constexpr int ITERS = Kdim / 128;   // 32 iterations, 2 K-tiles (BK=64) each

__device__ __forceinline__ unsigned short f2bf(float f) {
  unsigned u = __builtin_bit_cast(unsigned, f);
  u += 0x7fffu + ((u >> 16) & 1u);   // RNE (finite inputs)
  return (unsigned short)(u >> 16);
}

__device__ __forceinline__ void gload16(const unsigned short* g, const char* l) {
  __builtin_amdgcn_global_load_lds(
      (const __attribute__((address_space(1))) unsigned int*)g,
      (__attribute__((address_space(3))) unsigned int*)(char*)l, 16, 0, 0);
}

// ---------------- fused conversion (memory-bound) ----------------

__global__ __launch_bounds__(256) void cvt_kernel(const float* __restrict__ x,
                                                  const float* __restrict__ qw,
                                                  const float* __restrict__ scale,
                                                  unsigned short* __restrict__ xb,
                                                  unsigned short* __restrict__ wb) {
  const long NX = (long)Mdim * Kdim / 8;   // 4194304
  long i = (long)blockIdx.x * 256 + threadIdx.x;
  if (i < NX) {
    f32x4 a = ((const f32x4*)x)[2 * i];
    f32x4 b = ((const f32x4*)x)[2 * i + 1];
    u16x8 o;
    o[0] = f2bf(a[0]); o[1] = f2bf(a[1]); o[2] = f2bf(a[2]); o[3] = f2bf(a[3]);
    o[4] = f2bf(b[0]); o[5] = f2bf(b[1]); o[6] = f2bf(b[2]); o[7] = f2bf(b[3]);
    ((u16x8*)xb)[i] = o;
  } else {
    long j = i - NX;
    const float s = scale[j >> 9];          // 512 chunks per weight row
    f32x4 a = ((const f32x4*)qw)[2 * j];
    f32x4 b = ((const f32x4*)qw)[2 * j + 1];
    u16x8 o;
    o[0] = f2bf(a[0] * s); o[1] = f2bf(a[1] * s); o[2] = f2bf(a[2] * s); o[3] = f2bf(a[3] * s);
    o[4] = f2bf(b[0] * s); o[5] = f2bf(b[1] * s); o[6] = f2bf(b[2] * s); o[7] = f2bf(b[3] * s);
    ((u16x8*)wb)[j] = o;
  }
}

// ---------------- GEMM ----------------
// LDS 128KB dynamic: A [0,64K) (buf0=even K-tile, buf1=odd), B [64K,128K).
// Tile (256 x 64, 32KB): (row r, 16B-chunk ch) at byte r*128 + (ch ^ (r&7))*16.
// Staging dest LINEAR (inverse swizzle on global src).
// Waves 8 = 2M x 4N interleaved: m-frag i at row i*32+wr*16, n-frag j at
// col j*64+wc*16. Per phase: one C-quadrant x K=64 = 16 MFMA.
//
// LDS reads per phase: ph1 A0h0+B0h0, ph2 B0h1, ph3 A0h1, ph4 regs-only,
//                      ph5 A1h0+B1h0, ph6 B1h1, ph7 A1h1, ph8 regs-only.
// Stage per phase (region's last reader drained >=1 barrier earlier):
//  ph1 A1h1(t1)  ph2 A0h0(t2)  ph3 B0h0(t2)  ph4 B0h1(t2)
//  ph5 A0h1(t2)  ph6 A1h0(t3)  ph7 B1h0(t3)  ph8 B1h1(t3)
// vmcnt(6) at ph4 end (drains through ph1 -> odd tile t1 fully resident for
// ph5) and ph8 end (drains through ph5 -> even tile t2 resident for next ph1);
// steady-state in-flight = {A1h0,B1h0,B1h1}(next odd tile) = 6 loads, matching
// the prologue. ONE barrier per phase: each wave's ds_reads are compiler-
// drained before its MFMAs, hence complete before it reaches the barrier, so
// stages issued after the barrier cannot race prior-phase reads.

#define FBAR() do { asm volatile("" ::: "memory"); \
                    __builtin_amdgcn_s_barrier(); \
                    asm volatile("" ::: "memory"); } while (0)

#define MMQ(mo, no, bf) do { \
  __builtin_amdgcn_s_setprio(1); \
  _Pragma("unroll") for (int m_ = 0; m_ < 4; ++m_) \
  _Pragma("unroll") for (int n_ = 0; n_ < 2; ++n_) \
  _Pragma("unroll") for (int s_ = 0; s_ < 2; ++s_) \
    acc[(mo) + m_][(no) + n_] = __builtin_amdgcn_mfma_f32_16x16x32_bf16( \
        af[m_][s_], bf[n_][s_], acc[(mo) + m_][(no) + n_], 0, 0, 0); \
  __builtin_amdgcn_s_setprio(0); \
} while (0)

#define RDA(base, mb) do { \
  _Pragma("unroll") for (int m_ = 0; m_ < 4; ++m_) { \
    af[m_][0] = *(const bf16x8*)((base) + ((mb) + m_) * 4096 + rowbA + cs0); \
    af[m_][1] = *(const bf16x8*)((base) + ((mb) + m_) * 4096 + rowbA + (cs0 ^ 64)); \
  } } while (0)

#define RDB(base, nb, bf) do { \
  _Pragma("unroll") for (int n_ = 0; n_ < 2; ++n_) { \
    bf[n_][0] = *(const bf16x8*)((base) + ((nb) + n_) * 8192 + rowbB + cs0); \
    bf[n_][1] = *(const bf16x8*)((base) + ((nb) + n_) * 8192 + rowbB + (cs0 ^ 64)); \
  } } while (0)

// stage half h (global rows h*128..h*128+127) of K-tile T into LDS slot
// base + h*16384 (linear dest; 2 x global_load_lds_dwordx4 per thread)
#define STG(p, h, T, base) do { \
  gload16((p) + ((size_t)((h) * 128)) * Kdim + (T) * 64, (base) + (h) * 16384 + wb1024); \
  gload16((p) + ((size_t)((h) * 128 + 64)) * Kdim + (T) * 64, (base) + (h) * 16384 + 8192 + wb1024); \
} while (0)

__global__ __launch_bounds__(512, 2) void gemm_kernel(const unsigned short* __restrict__ A,
                                                      const unsigned short* __restrict__ B,
                                                      float* __restrict__ C) {
  extern __shared__ char lds[];
  char* A0 = lds;
  char* A1 = lds + 32768;
  char* B0 = lds + 65536;
  char* B1 = lds + 98304;

  const int th = threadIdx.x, w = th >> 6, l = th & 63;
  const int wr = w & 1, wc = w >> 1;
  const int wb1024 = w * 1024;

  // XCD-bijective swizzle (512 blocks, 512 % 8 == 0)
  int wg = (int)blockIdx.x;
  wg = (wg & 7) * 64 + (wg >> 3);
  const int bm = wg >> 4, bn = wg & 15;

  // staging source (inverse-swizzled): thread th supplies LDS-linear byte th*16 of a half
  const int kc8 = ((th & 7) ^ ((th >> 3) & 7)) * 8;
  const unsigned short* pA = A + (size_t)(bm * 256 + (th >> 3)) * Kdim + kc8;
  const unsigned short* pB = B + (size_t)(bn * 256 + (th >> 3)) * Kdim + kc8;

  // fragment read offsets (swizzled)
  const int rowbA = (wr * 16 + (l & 15)) * 128;
  const int rowbB = (wc * 16 + (l & 15)) * 128;
  const int cs0   = ((l >> 4) ^ (l & 7)) * 16;   // kstep1 offset = cs0 ^ 64

  f32x4 acc[8][4] = {};
  bf16x8 af[4][2], bf0[2][2], bf1[2][2];

  // prologue: tile0 fully (8 loads, oldest), then tile1 A1h0, B1h0, B1h1
  STG(pA, 0, 0, A0); STG(pA, 1, 0, A0);
  STG(pB, 0, 0, B0); STG(pB, 1, 0, B0);
  STG(pA, 0, 1, A1);
  STG(pB, 0, 1, B1);
  STG(pB, 1, 1, B1);
  asm volatile("s_waitcnt vmcnt(6)" ::: "memory");
  __builtin_amdgcn_s_barrier();

#pragma unroll 1
  for (int i = 0; i < ITERS - 1; ++i) {
    const int t1 = 2 * i + 1, t2 = 2 * i + 2, t3 = 2 * i + 3;
    // ph1: RD A0h0,B0h0 | STG A1h1(t1)
    RDA(A0, 0); RDB(B0, 0, bf0);
    STG(pA, 1, t1, A1);
    MMQ(0, 0, bf0); FBAR();
    // ph2: RD B0h1 | STG A0h0(t2)
    RDB(B0, 2, bf1);
    STG(pA, 0, t2, A0);
    MMQ(0, 2, bf1); FBAR();
    // ph3: RD A0h1 | STG B0h0(t2)
    RDA(A0, 4);
    STG(pB, 0, t2, B0);
    MMQ(4, 2, bf1); FBAR();
    // ph4: regs-only | STG B0h1(t2) | vmcnt(6) -> tile t1 resident
    STG(pB, 1, t2, B0);
    MMQ(4, 0, bf0);
    asm volatile("s_waitcnt vmcnt(6)" ::: "memory");
    FBAR();
    // ph5: RD A1h0,B1h0 | STG A0h1(t2)
    RDA(A1, 0); RDB(B1, 0, bf0);
    STG(pA, 1, t2, A0);
    MMQ(0, 0, bf0); FBAR();
    // ph6: RD B1h1 | STG A1h0(t3)
    RDB(B1, 2, bf1);
    STG(pA, 0, t3, A1);
    MMQ(0, 2, bf1); FBAR();
    // ph7: RD A1h1 | STG B1h0(t3)
    RDA(A1, 4);
    STG(pB, 0, t3, B1);
    MMQ(4, 2, bf1); FBAR();
    // ph8: regs-only | STG B1h1(t3) | vmcnt(6) -> tile t2 resident
    STG(pB, 1, t3, B1);
    MMQ(4, 0, bf0);
    asm volatile("s_waitcnt vmcnt(6)" ::: "memory");
    FBAR();
  }

  // tail iteration (tiles 62,63): stage only ph1 (A1h1 of 63), vmcnt(0) at ph4
  {
    RDA(A0, 0); RDB(B0, 0, bf0);
    STG(pA, 1, 63, A1);
    MMQ(0, 0, bf0); FBAR();
    RDB(B0, 2, bf1);
    MMQ(0, 2, bf1); FBAR();
    RDA(A0, 4);
    MMQ(4, 2, bf1); FBAR();
    MMQ(4, 0, bf0);
    asm volatile("s_waitcnt vmcnt(0)" ::: "memory");
    FBAR();
    RDA(A1, 0); RDB(B1, 0, bf0);
    MMQ(0, 0, bf0); FBAR();
    RDB(B1, 2, bf1);
    MMQ(0, 2, bf1); FBAR();
    RDA(A1, 4);
    MMQ(4, 2, bf1); FBAR();
    MMQ(4, 0, bf0);
  }

  // ---------------- epilogue: LDS-shuffled coalesced fp32 stores ----------------
  // Two half-passes of 128 rows x 256 cols fp32 = 128 KB (exactly the LDS).
  // acc frag (i,j): C row = i*32 + wr*16 + (l>>4)*4 + rr, col = j*64 + wc*16 + (l&15).
  // LDS f32 addr: lr*256 + ((grp ^ (lr&7))<<2) + (c&3), grp = c>>2. Writes
  // <=2-way conflict (free); reads 256B-contiguous per 16-lane group -> nt dwordx4.
  float* ldsf = (float*)lds;
  const int r0q = (l >> 4) * 4;
  const int ccol = wc * 16 + (l & 15);
  __syncthreads();   // K-loop fully done
#pragma unroll
  for (int h = 0; h < 2; ++h) {
    if (h) __syncthreads();
#pragma unroll
    for (int i4 = 0; i4 < 4; ++i4)
#pragma unroll
      for (int j = 0; j < 4; ++j) {
        const int lr0 = i4 * 32 + wr * 16 + r0q;
        const int c   = j * 64 + ccol;
        const int grp = c >> 2, win = c & 3;
#pragma unroll
        for (int rr = 0; rr < 4; ++rr) {
          const int lr = lr0 + rr;
          ldsf[lr * 256 + ((grp ^ (lr & 7)) << 2) + win] = acc[h * 4 + i4][j][rr];
        }
      }
    __syncthreads();
#pragma unroll
    for (int jj = 0; jj < 4; ++jj)
#pragma unroll
      for (int k = 0; k < 4; ++k) {
        const int lr = w * 16 + (l >> 4) + 4 * jj;
        const int g  = (l & 15) + 16 * k;
        f32x4 v = *(const f32x4*)&ldsf[lr * 256 + ((g ^ (lr & 7)) << 2)];
        float* cp = C + (size_t)(bm * 256 + h * 128 + lr) * Ndim + bn * 256 + 4 * g;
        __builtin_nontemporal_store(v, (f32x4*)cp);
      }
  }
}

extern "C" void kernel_launch(void* const* d_in, const int* in_sizes, int n_in,
                              void* d_out, int out_size, void* d_ws, size_t ws_size,
                              hipStream_t stream) {
  const float* x     = (const float*)d_in[0];
  const float* qw    = (const float*)d_in[1];
  const float* scale = (const float*)d_in[2];
  float* out = (float*)d_out;

  unsigned short* xb = (unsigned short*)d_ws;                 // 67.1 MB
  unsigned short* wb = xb + (size_t)Mdim * Kdim;              // +33.6 MB

  (void)hipFuncSetAttribute((const void*)gemm_kernel,
                            hipFuncAttributeMaxDynamicSharedMemorySize, 131072);

  const long nchunks = (long)Mdim * Kdim / 8 + (long)Ndim * Kdim / 8;  // 6291456
  cvt_kernel<<<(int)(nchunks / 256), 256, 0, stream>>>(x, qw, scale, xb, wb);

  gemm_kernel<<<(Mdim / 256) * (Ndim / 256), 512, 131072, stream>>>(xb, wb, out);
}